// Round 3
// baseline (541.482 us; speedup 1.0000x reference)
//
#include <hip/hip_runtime.h>
#include <hip/hip_bf16.h>

// B=16, C=512, H=W=64, N=4096
#define CCH  512
#define NTOK 4096
#define NB   16
#define KSPL 2048          // split-K half length for energy GEMM
#define LDA  40            // padded LDS row stride (shorts) for VGPR-staged A tiles

typedef __attribute__((ext_vector_type(8))) short s8v;   // 8 bf16 (4 VGPRs)
typedef __attribute__((ext_vector_type(4))) float f4v;   // 4 fp32 acc
typedef unsigned short u16;

__device__ __forceinline__ void split2(float2 f, ushort2& hi, ushort2& lo) {
    __hip_bfloat162 h = __float22bfloat162_rn(f);
    float2 hf = __bfloat1622float2(h);
    __hip_bfloat162 l = __float22bfloat162_rn(make_float2(f.x - hf.x, f.y - hf.y));
    hi = *reinterpret_cast<ushort2*>(&h);
    lo = *reinterpret_cast<ushort2*>(&l);
}
__device__ __forceinline__ u16 bfrne(float x) {
    __hip_bfloat16 h = __float2bfloat16(x);
    return *reinterpret_cast<u16*>(&h);
}
// async global->LDS, 16B per lane; LDS dest = wave-uniform base + lane*16
__device__ __forceinline__ void dma16(const void* g, void* l) {
    __builtin_amdgcn_global_load_lds((const __attribute__((address_space(1))) void*)g,
                                     (__attribute__((address_space(3))) void*)l, 16, 0, 0);
}

// ---------------------------------------------------------------------------
// P: kv fp32 -> kvh, kvl (bf16 [c][n]) + kvT (bf16-hi [n][c], for K3 B operand)
// 64x64 tiles, LDS transpose for kvT. Pure streaming, ~320 MiB total.
// ---------------------------------------------------------------------------
__global__ __launch_bounds__(256)
void convert_kv(const float* __restrict__ kv, u16* __restrict__ kvh,
                u16* __restrict__ kvl, u16* __restrict__ kvT) {
    __shared__ u16 T[64][72];
    const int b = blockIdx.z, c0 = blockIdx.y * 64, n0 = blockIdx.x * 64;
    const int t = threadIdx.x;
    const int r = t >> 2, cs = (t & 3) * 16;
    const float* src = kv + ((size_t)(b * CCH + c0 + r)) * NTOK + n0 + cs;
    u16 hi[16], lo[16];
#pragma unroll
    for (int p = 0; p < 4; ++p) {
        float4 v = ((const float4*)src)[p];
        ushort2 h0, l0, h1, l1;
        split2(make_float2(v.x, v.y), h0, l0);
        split2(make_float2(v.z, v.w), h1, l1);
        hi[p*4+0]=h0.x; hi[p*4+1]=h0.y; hi[p*4+2]=h1.x; hi[p*4+3]=h1.y;
        lo[p*4+0]=l0.x; lo[p*4+1]=l0.y; lo[p*4+2]=l1.x; lo[p*4+3]=l1.y;
    }
    u16* dh = kvh + ((size_t)(b * CCH + c0 + r)) * NTOK + n0 + cs;
    u16* dl = kvl + ((size_t)(b * CCH + c0 + r)) * NTOK + n0 + cs;
#pragma unroll
    for (int p = 0; p < 4; ++p) {
        *(ushort4*)(dh + p*4) = make_ushort4(hi[p*4], hi[p*4+1], hi[p*4+2], hi[p*4+3]);
        *(ushort4*)(dl + p*4) = make_ushort4(lo[p*4], lo[p*4+1], lo[p*4+2], lo[p*4+3]);
    }
#pragma unroll
    for (int k = 0; k < 16; ++k) T[cs + k][r] = hi[k];
    __syncthreads();
    const int n1 = t >> 2, ccs = (t & 3) * 16;
    u16* dt = kvT + ((size_t)(b * NTOK + n0 + n1)) * CCH + c0 + ccs;
#pragma unroll
    for (int p = 0; p < 4; ++p)
        *(ushort4*)(dt + p*4) = *(const ushort4*)&T[n1][ccs + p*4];
}

// ---------------------------------------------------------------------------
// K1 v3: E[s][b] partial = q[b,c,:] . kv[b,d,:] over K-split s.
// A (q): in-kernel split, VGPR staging, padded LDS. B (kvh/kvl): DMA staging,
// unpadded LDS with XOR granule swizzle slot = kg ^ ((row>>1)&3) (2-way reads).
// ---------------------------------------------------------------------------
__global__ __launch_bounds__(256, 2)
void energy_v3(const float* __restrict__ q, const u16* __restrict__ kvh,
               const u16* __restrict__ kvl, float* __restrict__ E) {
    __shared__ short Ah[128 * LDA], Al[128 * LDA];
    __shared__ __align__(16) char Bh[8192], Bl[8192];
    const int b = blockIdx.z >> 1, s = blockIdx.z & 1;
    const int c0 = blockIdx.y * 128, d0 = blockIdx.x * 128;
    const int tid = threadIdx.x, lane = tid & 63, wave = tid >> 6;
    const int wm = wave & 1, wn = wave >> 1;
    const int l15 = lane & 15, quad = lane >> 4;

    // A staging map
    const int srow = tid >> 1, skq = (tid & 1) * 16;
    const float* ga = q + ((size_t)(b * CCH + c0 + srow)) * NTOK + s * KSPL + skq;
    // B DMA map: lane -> row wave*32 + (lane>>2) (+16 for call 1), granule gl
    const int drow = wave * 32 + (lane >> 2);
    const int gl   = (lane & 3) ^ ((lane >> 3) & 3);
    const u16* gbh = kvh + ((size_t)(b * CCH + d0 + drow)) * NTOK + s * KSPL + gl * 8;
    const u16* gbl = kvl + ((size_t)(b * CCH + d0 + drow)) * NTOK + s * KSPL + gl * 8;
    char* ldsBh = Bh + wave * 2048;
    char* ldsBl = Bl + wave * 2048;

    f4v acc[4][4];
#pragma unroll
    for (int i = 0; i < 4; ++i)
#pragma unroll
        for (int j = 0; j < 4; ++j) acc[i][j] = (f4v)0.f;

    float4 pa[4];
#pragma unroll
    for (int i = 0; i < 4; ++i) pa[i] = ((const float4*)ga)[i];

    for (int kc = 0; kc < KSPL; kc += 32) {
        __syncthreads();
        // B: async DMA (issued first, longest latency)
        dma16(gbh + kc, ldsBh);
        dma16(gbh + 16 * NTOK + kc, ldsBh + 1024);
        dma16(gbl + kc, ldsBl);
        dma16(gbl + 16 * NTOK + kc, ldsBl + 1024);
        // A: split + LDS write
#pragma unroll
        for (int i = 0; i < 4; ++i) {
            ushort2 h0, l0, h1, l1;
            split2(make_float2(pa[i].x, pa[i].y), h0, l0);
            split2(make_float2(pa[i].z, pa[i].w), h1, l1);
            *(ushort4*)&Ah[srow * LDA + skq + i * 4] = make_ushort4(h0.x, h0.y, h1.x, h1.y);
            *(ushort4*)&Al[srow * LDA + skq + i * 4] = make_ushort4(l0.x, l0.y, l1.x, l1.y);
        }
        __syncthreads();
        if (kc + 32 < KSPL) {
            const float* ga2 = ga + kc + 32;
#pragma unroll
            for (int i = 0; i < 4; ++i) pa[i] = ((const float4*)ga2)[i];
        }
        const int aoff  = (wm * 64 + l15) * LDA + quad * 8;
        const int xslot = quad ^ ((l15 >> 1) & 3);
        const int boff  = (wn * 64 + l15) * 64 + xslot * 16;
        s8v a_h[4], a_l[4];
#pragma unroll
        for (int i = 0; i < 4; ++i) {
            a_h[i] = *(const s8v*)&Ah[aoff + i * 16 * LDA];
            a_l[i] = *(const s8v*)&Al[aoff + i * 16 * LDA];
        }
#pragma unroll
        for (int j = 0; j < 4; ++j) {
            s8v b_h = *(const s8v*)(Bh + boff + j * 1024);
            s8v b_l = *(const s8v*)(Bl + boff + j * 1024);
#pragma unroll
            for (int i = 0; i < 4; ++i) {
                acc[i][j] = __builtin_amdgcn_mfma_f32_16x16x32_bf16(a_h[i], b_h, acc[i][j], 0, 0, 0);
                acc[i][j] = __builtin_amdgcn_mfma_f32_16x16x32_bf16(a_h[i], b_l, acc[i][j], 0, 0, 0);
                acc[i][j] = __builtin_amdgcn_mfma_f32_16x16x32_bf16(a_l[i], b_h, acc[i][j], 0, 0, 0);
            }
        }
    }

    float* Eb = E + ((size_t)(s * NB + b)) * CCH * CCH;
#pragma unroll
    for (int i = 0; i < 4; ++i)
#pragma unroll
        for (int r = 0; r < 4; ++r) {
            const int row = c0 + wm * 64 + i * 16 + quad * 4 + r;
#pragma unroll
            for (int j = 0; j < 4; ++j)
                Eb[(size_t)row * CCH + d0 + wn * 64 + j * 16 + l15] = acc[i][j][r];
        }
}

// ---------------------------------------------------------------------------
// K2: att = softmax(min - e), e = E0 + E1. Emits att bf16 hi + lo.
// ---------------------------------------------------------------------------
__global__ __launch_bounds__(256)
void attn_softmax(const float* __restrict__ E0, const float* __restrict__ E1,
                  u16* __restrict__ ah, u16* __restrict__ al) {
    __shared__ float red[4];
    const size_t base = (size_t)blockIdx.x * CCH;
    const int t = threadIdx.x;
    float e0 = E0[base + t] + E1[base + t];
    float e1 = E0[base + t + 256] + E1[base + t + 256];
    float m = fminf(e0, e1);
#pragma unroll
    for (int off = 32; off > 0; off >>= 1) m = fminf(m, __shfl_xor(m, off, 64));
    if ((t & 63) == 0) red[t >> 6] = m;
    __syncthreads();
    const float mAll = fminf(fminf(red[0], red[1]), fminf(red[2], red[3]));
    float x0 = __expf(mAll - e0);
    float x1 = __expf(mAll - e1);
    float sum = x0 + x1;
#pragma unroll
    for (int off = 32; off > 0; off >>= 1) sum += __shfl_xor(sum, off, 64);
    __syncthreads();
    if ((t & 63) == 0) red[t >> 6] = sum;
    __syncthreads();
    const float inv = 1.0f / (red[0] + red[1] + red[2] + red[3]);
    float a0 = x0 * inv, a1 = x1 * inv;
    __hip_bfloat16 h0 = __float2bfloat16(a0);
    __hip_bfloat16 h1 = __float2bfloat16(a1);
    ah[base + t]       = *reinterpret_cast<u16*>(&h0);
    ah[base + t + 256] = *reinterpret_cast<u16*>(&h1);
    __hip_bfloat16 g0 = __float2bfloat16(a0 - __bfloat162float(h0));
    __hip_bfloat16 g1 = __float2bfloat16(a1 - __bfloat162float(h1));
    al[base + t]       = *reinterpret_cast<u16*>(&g0);
    al[base + t + 256] = *reinterpret_cast<u16*>(&g1);
}

// ---------------------------------------------------------------------------
// K3 v3: out = att * kv with fused softmax over W=64. All-bf16 DMA staging:
// A = ath/atl [c][d] (k=d contiguous), B = kvT [n][c] (k=c contiguous).
// ---------------------------------------------------------------------------
__global__ __launch_bounds__(256, 2)
void out_v3(const u16* __restrict__ ath, const u16* __restrict__ atl,
            const u16* __restrict__ kvT, float* __restrict__ out) {
    __shared__ __align__(16) char Ah[8192], Al[8192], Bs[8192];
    const int b = blockIdx.z, c0 = blockIdx.y * 128, n0 = blockIdx.x * 128;
    const int tid = threadIdx.x, lane = tid & 63, wave = tid >> 6;
    const int wm = wave & 1, wn = wave >> 1;
    const int l15 = lane & 15, quad = lane >> 4;

    const int grow = wave * 32 + (lane >> 2);
    const int gl   = (lane & 3) ^ ((lane >> 3) & 3);
    const u16* gah = ath + ((size_t)(b * CCH + c0 + grow)) * CCH + gl * 8;
    const u16* gal = atl + ((size_t)(b * CCH + c0 + grow)) * CCH + gl * 8;
    const u16* gbt = kvT + ((size_t)(b * NTOK + n0 + grow)) * CCH + gl * 8;
    char* ldsA  = Ah + wave * 2048;
    char* ldsAl = Al + wave * 2048;
    char* ldsB  = Bs + wave * 2048;

    f4v acc[4][4];
#pragma unroll
    for (int i = 0; i < 4; ++i)
#pragma unroll
        for (int j = 0; j < 4; ++j) acc[i][j] = (f4v)0.f;

    for (int kc = 0; kc < CCH; kc += 32) {
        __syncthreads();
        dma16(gah + kc, ldsA);
        dma16(gah + 16 * CCH + kc, ldsA + 1024);
        dma16(gal + kc, ldsAl);
        dma16(gal + 16 * CCH + kc, ldsAl + 1024);
        dma16(gbt + kc, ldsB);
        dma16(gbt + 16 * CCH + kc, ldsB + 1024);
        __syncthreads();
        const int xslot = quad ^ ((l15 >> 1) & 3);
        const int aoff  = (wm * 64 + l15) * 64 + xslot * 16;
        const int boff  = (wn * 64 + l15) * 64 + xslot * 16;
        s8v a_h[4], a_l[4];
#pragma unroll
        for (int i = 0; i < 4; ++i) {
            a_h[i] = *(const s8v*)(Ah + aoff + i * 1024);
            a_l[i] = *(const s8v*)(Al + aoff + i * 1024);
        }
#pragma unroll
        for (int j = 0; j < 4; ++j) {
            s8v bb = *(const s8v*)(Bs + boff + j * 1024);
#pragma unroll
            for (int i = 0; i < 4; ++i) {
                acc[i][j] = __builtin_amdgcn_mfma_f32_16x16x32_bf16(a_h[i], bb, acc[i][j], 0, 0, 0);
                acc[i][j] = __builtin_amdgcn_mfma_f32_16x16x32_bf16(a_l[i], bb, acc[i][j], 0, 0, 0);
            }
        }
    }

    // fused softmax over W=64 (this wave's 64-col group lives in j-regs + l15)
#pragma unroll
    for (int i = 0; i < 4; ++i) {
#pragma unroll
        for (int r = 0; r < 4; ++r) {
            float v0 = acc[i][0][r], v1 = acc[i][1][r], v2 = acc[i][2][r], v3 = acc[i][3][r];
            float m = fmaxf(fmaxf(v0, v1), fmaxf(v2, v3));
#pragma unroll
            for (int off = 8; off > 0; off >>= 1) m = fmaxf(m, __shfl_xor(m, off, 16));
            float e0 = __expf(v0 - m), e1 = __expf(v1 - m), e2 = __expf(v2 - m), e3 = __expf(v3 - m);
            float sum = e0 + e1 + e2 + e3;
#pragma unroll
            for (int off = 8; off > 0; off >>= 1) sum += __shfl_xor(sum, off, 16);
            const float inv = 1.0f / sum;
            const int row = c0 + wm * 64 + i * 16 + quad * 4 + r;
            float* op = out + ((size_t)(b * CCH + row)) * NTOK + n0 + wn * 64 + l15;
            op[0]  = e0 * inv;
            op[16] = e1 * inv;
            op[32] = e2 * inv;
            op[48] = e3 * inv;
        }
    }
}

// ---------------------------------------------------------------------------
// R2 fallback kernels (used only if ws_size < 240 MiB)
// ---------------------------------------------------------------------------
__global__ __launch_bounds__(256, 2)
void energy_r2(const float* __restrict__ q, const float* __restrict__ kv,
               float* __restrict__ E) {
    __shared__ short Ah[128 * LDA], Al[128 * LDA], Bh[128 * LDA], Bl[128 * LDA];
    const int b = blockIdx.z >> 1, s = blockIdx.z & 1;
    const int c0 = blockIdx.y * 128, d0 = blockIdx.x * 128;
    const int tid = threadIdx.x, lane = tid & 63, wave = tid >> 6;
    const int wm = wave & 1, wn = wave >> 1;
    const int l15 = lane & 15, quad = lane >> 4;
    const int srow = tid >> 1, skq = (tid & 1) * 16;
    const float* ga = q  + ((size_t)(b * CCH + c0 + srow)) * NTOK + s * KSPL + skq;
    const float* gb = kv + ((size_t)(b * CCH + d0 + srow)) * NTOK + s * KSPL + skq;
    f4v acc[4][4];
#pragma unroll
    for (int i = 0; i < 4; ++i)
#pragma unroll
        for (int j = 0; j < 4; ++j) acc[i][j] = (f4v)0.f;
    float4 pa[4], pb[4];
#pragma unroll
    for (int i = 0; i < 4; ++i) { pa[i] = ((const float4*)ga)[i]; pb[i] = ((const float4*)gb)[i]; }
    for (int kc = 0; kc < KSPL; kc += 32) {
        __syncthreads();
#pragma unroll
        for (int i = 0; i < 4; ++i) {
            ushort2 h0, l0, h1, l1;
            split2(make_float2(pa[i].x, pa[i].y), h0, l0);
            split2(make_float2(pa[i].z, pa[i].w), h1, l1);
            *(ushort4*)&Ah[srow * LDA + skq + i * 4] = make_ushort4(h0.x, h0.y, h1.x, h1.y);
            *(ushort4*)&Al[srow * LDA + skq + i * 4] = make_ushort4(l0.x, l0.y, l1.x, l1.y);
            split2(make_float2(pb[i].x, pb[i].y), h0, l0);
            split2(make_float2(pb[i].z, pb[i].w), h1, l1);
            *(ushort4*)&Bh[srow * LDA + skq + i * 4] = make_ushort4(h0.x, h0.y, h1.x, h1.y);
            *(ushort4*)&Bl[srow * LDA + skq + i * 4] = make_ushort4(l0.x, l0.y, l1.x, l1.y);
        }
        __syncthreads();
        if (kc + 32 < KSPL) {
            const float* ga2 = ga + kc + 32; const float* gb2 = gb + kc + 32;
#pragma unroll
            for (int i = 0; i < 4; ++i) { pa[i] = ((const float4*)ga2)[i]; pb[i] = ((const float4*)gb2)[i]; }
        }
        const int aoff = (wm * 64 + l15) * LDA + quad * 8;
        const int boff = (wn * 64 + l15) * LDA + quad * 8;
        s8v a_h[4], a_l[4];
#pragma unroll
        for (int i = 0; i < 4; ++i) {
            a_h[i] = *(const s8v*)&Ah[aoff + i * 16 * LDA];
            a_l[i] = *(const s8v*)&Al[aoff + i * 16 * LDA];
        }
#pragma unroll
        for (int j = 0; j < 4; ++j) {
            s8v b_h = *(const s8v*)&Bh[boff + j * 16 * LDA];
            s8v b_l = *(const s8v*)&Bl[boff + j * 16 * LDA];
#pragma unroll
            for (int i = 0; i < 4; ++i) {
                acc[i][j] = __builtin_amdgcn_mfma_f32_16x16x32_bf16(a_h[i], b_h, acc[i][j], 0, 0, 0);
                acc[i][j] = __builtin_amdgcn_mfma_f32_16x16x32_bf16(a_h[i], b_l, acc[i][j], 0, 0, 0);
                acc[i][j] = __builtin_amdgcn_mfma_f32_16x16x32_bf16(a_l[i], b_h, acc[i][j], 0, 0, 0);
            }
        }
    }
    float* Eb = E + ((size_t)(s * NB + b)) * CCH * CCH;
#pragma unroll
    for (int i = 0; i < 4; ++i)
#pragma unroll
        for (int r = 0; r < 4; ++r) {
            const int row = c0 + wm * 64 + i * 16 + quad * 4 + r;
#pragma unroll
            for (int j = 0; j < 4; ++j)
                Eb[(size_t)row * CCH + d0 + wn * 64 + j * 16 + l15] = acc[i][j][r];
        }
}

__global__ __launch_bounds__(256, 2)
void out_r2(const u16* __restrict__ atth, const u16* __restrict__ attl,
            const float* __restrict__ kv, float* __restrict__ out) {
    __shared__ short Ah[128 * LDA], Al[128 * LDA], Bs[128 * LDA];
    const int b = blockIdx.z, c0 = blockIdx.y * 128, n0 = blockIdx.x * 128;
    const int tid = threadIdx.x, lane = tid & 63, wave = tid >> 6;
    const int wm = wave & 1, wn = wave >> 1;
    const int l15 = lane & 15, quad = lane >> 4;
    const int arow = tid >> 1, akq = (tid & 1) * 16;
    const u16* gah = atth + ((size_t)(b * CCH + c0 + arow)) * CCH + akq;
    const u16* gal = attl + ((size_t)(b * CCH + c0 + arow)) * CCH + akq;
    const int bn = tid & 127, bkg = (tid >> 7) * 16;
    const float* gb = kv + (size_t)b * CCH * NTOK + n0 + bn;
    f4v acc[4][4];
#pragma unroll
    for (int i = 0; i < 4; ++i)
#pragma unroll
        for (int j = 0; j < 4; ++j) acc[i][j] = (f4v)0.f;
    ushort4 pah[4], pal[4];
    float pbf[16];
#pragma unroll
    for (int i = 0; i < 4; ++i) { pah[i] = *(const ushort4*)(gah + i * 4); pal[i] = *(const ushort4*)(gal + i * 4); }
#pragma unroll
    for (int t = 0; t < 16; ++t) pbf[t] = gb[(size_t)(bkg + t) * NTOK];
    for (int kc = 0; kc < CCH; kc += 32) {
        __syncthreads();
#pragma unroll
        for (int i = 0; i < 4; ++i) {
            *(ushort4*)&Ah[arow * LDA + akq + i * 4] = pah[i];
            *(ushort4*)&Al[arow * LDA + akq + i * 4] = pal[i];
        }
#pragma unroll
        for (int p = 0; p < 4; ++p) {
            ushort4 v = make_ushort4(bfrne(pbf[p*4+0]), bfrne(pbf[p*4+1]), bfrne(pbf[p*4+2]), bfrne(pbf[p*4+3]));
            *(ushort4*)&Bs[bn * LDA + bkg + p * 4] = v;
        }
        __syncthreads();
        if (kc + 32 < CCH) {
#pragma unroll
            for (int i = 0; i < 4; ++i) { pah[i] = *(const ushort4*)(gah + kc + 32 + i * 4); pal[i] = *(const ushort4*)(gal + kc + 32 + i * 4); }
#pragma unroll
            for (int t = 0; t < 16; ++t) pbf[t] = gb[(size_t)(kc + 32 + bkg + t) * NTOK];
        }
        const int aoff = (wm * 64 + l15) * LDA + quad * 8;
        const int boff = (wn * 64 + l15) * LDA + quad * 8;
        s8v a_h[4], a_l[4];
#pragma unroll
        for (int i = 0; i < 4; ++i) {
            a_h[i] = *(const s8v*)&Ah[aoff + i * 16 * LDA];
            a_l[i] = *(const s8v*)&Al[aoff + i * 16 * LDA];
        }
#pragma unroll
        for (int j = 0; j < 4; ++j) {
            s8v bb = *(const s8v*)&Bs[boff + j * 16 * LDA];
#pragma unroll
            for (int i = 0; i < 4; ++i) {
                acc[i][j] = __builtin_amdgcn_mfma_f32_16x16x32_bf16(a_h[i], bb, acc[i][j], 0, 0, 0);
                acc[i][j] = __builtin_amdgcn_mfma_f32_16x16x32_bf16(a_l[i], bb, acc[i][j], 0, 0, 0);
            }
        }
    }
#pragma unroll
    for (int i = 0; i < 4; ++i) {
#pragma unroll
        for (int r = 0; r < 4; ++r) {
            float v0 = acc[i][0][r], v1 = acc[i][1][r], v2 = acc[i][2][r], v3 = acc[i][3][r];
            float m = fmaxf(fmaxf(v0, v1), fmaxf(v2, v3));
#pragma unroll
            for (int off = 8; off > 0; off >>= 1) m = fmaxf(m, __shfl_xor(m, off, 16));
            float e0 = __expf(v0 - m), e1 = __expf(v1 - m), e2 = __expf(v2 - m), e3 = __expf(v3 - m);
            float sum = e0 + e1 + e2 + e3;
#pragma unroll
            for (int off = 8; off > 0; off >>= 1) sum += __shfl_xor(sum, off, 16);
            const float inv = 1.0f / sum;
            const int row = c0 + wm * 64 + i * 16 + quad * 4 + r;
            float* op = out + ((size_t)(b * CCH + row)) * NTOK + n0 + wn * 64 + l15;
            op[0] = e0 * inv; op[16] = e1 * inv; op[32] = e2 * inv; op[48] = e3 * inv;
        }
    }
}

// ---------------------------------------------------------------------------
extern "C" void kernel_launch(void* const* d_in, const int* in_sizes, int n_in,
                              void* d_out, int out_size, void* d_ws, size_t ws_size,
                              hipStream_t stream) {
    const float* x_training = (const float*)d_in[0];  // kv
    const float* x_pre      = (const float*)d_in[1];  // q
    float* out = (float*)d_out;
    const size_t ES = (size_t)NB * CCH * CCH;    // 4.19M
    const size_t KS = (size_t)NB * CCH * NTOK;   // 33.55M
    const size_t NEED = KS * 2 * 3 + ES * 4 * 2 + ES * 2 * 2;  // 240 MiB

    if (ws_size >= NEED) {
        u16*   kvh = (u16*)d_ws;
        u16*   kvl = kvh + KS;
        u16*   kvT = kvl + KS;
        float* E0  = (float*)(kvT + KS);
        float* E1  = E0 + ES;
        u16*   ath = (u16*)(E1 + ES);
        u16*   atl = ath + ES;
        convert_kv<<<dim3(NTOK/64, CCH/64, NB), 256, 0, stream>>>(x_training, kvh, kvl, kvT);
        energy_v3<<<dim3(4, 4, 32), 256, 0, stream>>>(x_pre, kvh, kvl, E0);
        attn_softmax<<<dim3(NB * CCH), 256, 0, stream>>>(E0, E1, ath, atl);
        out_v3<<<dim3(NTOK/128, CCH/128, NB), 256, 0, stream>>>(ath, atl, kvT, out);
    } else {
        float* E0  = (float*)d_ws;
        float* E1  = E0 + ES;
        u16*   ath = (u16*)(E1 + ES);
        u16*   atl = ath + ES;
        energy_r2<<<dim3(4, 4, 32), 256, 0, stream>>>(x_pre, x_training, E0);
        attn_softmax<<<dim3(NB * CCH), 256, 0, stream>>>(E0, E1, ath, atl);
        out_r2<<<dim3(NTOK/128, CCH/128, NB), 256, 0, stream>>>(ath, atl, x_training, out);
    }
}